// Round 1
// baseline (320.681 us; speedup 1.0000x reference)
//
#include <hip/hip_runtime.h>
#include <hip/hip_bf16.h>
#include <math.h>

// Problem constants: B=4,H=8,S=4096,D=128,BT=64
#define Gp  32      // B*H
#define Sp  4096
#define Dp  128
#define BTp 64
#define NCp 64      // S/BT

typedef __attribute__((ext_vector_type(8))) short bf16x8;
typedef __attribute__((ext_vector_type(4))) float f32x4;

#define MFMA(a,b,c) __builtin_amdgcn_mfma_f32_16x16x32_bf16((a),(b),(c),0,0,0)

#define STR 72    // transposed buffers (vt,kt) row stride, bf16 elems

__device__ inline unsigned pack2(float lo, float hi) {
    __hip_bfloat162 h = __float22bfloat162_rn(make_float2(lo, hi));  // v_cvt_pk_bf16_f32 on gfx950
    union { __hip_bfloat162 v; unsigned u; } t; t.v = h; return t.u;
}
__device__ inline float bflo(unsigned u) { union { unsigned u; float f; } t; t.u = u << 16; return t.f; }
__device__ inline float bfhi(unsigned u) { union { unsigned u; float f; } t; t.u = u & 0xffff0000u; return t.f; }

// ---------------------------------------------------------------------------
// Kernel A: intra-chunk output + transposed per-chunk state term (updT, bf16).
// 256 threads, LDS = 36.9 KB -> 4 blocks/CU.  ONE barrier.
// GEMM1 swapped (A=K from global, B=Q): lane holds P[j][i], i = 16w+m16.
// P transposed to GEMM2 B-fragments fully in-register (quad shuffles).
// GEMM3/GEMM2 swapped so stores vectorize (uint2 / float4).
// ---------------------------------------------------------------------------
__global__ __launch_bounds__(256, 4) void gdn_intra(
    const float* __restrict__ q, const float* __restrict__ k,
    const float* __restrict__ v, const float* __restrict__ beta,
    float* __restrict__ out, unsigned short* __restrict__ upd,
    float* __restrict__ tot_buf, float* __restrict__ dfs_buf)
{
    __shared__ unsigned short s_vt[128 * STR];  // v^T  [d][i]
    __shared__ unsigned short s_kt[128 * STR];  // (k*dte)^T [d][i]

    const int blk = blockIdx.x, g = blk >> 6, c = blk & 63;
    const int tid = threadIdx.x, lane = tid & 63, w = tid >> 6;
    const int m16 = lane & 15, quad = lane >> 4;
    const size_t base  = ((size_t)g * Sp + (size_t)c * BTp) * Dp;
    const size_t bbase = (size_t)g * Sp + (size_t)c * BTp;

    // every wave redundantly computes the 64-lane log-beta prefix (no LDS dep)
    float x = logf(beta[bbase + lane] + 1e-6f);
    #pragma unroll
    for (int off = 1; off < 64; off <<= 1) {
        float n = __shfl_up(x, off, 64);
        if (lane >= off) x += n;
    }
    const float tot = __shfl(x, 63, 64);
    const float dte_own = expf(tot - x);          // lane L holds dte[L]
    if (tid < 64) dfs_buf[bbase + lane] = expf(x);
    if (tid == 63) tot_buf[g * NCp + c] = tot;

    // stage v^T and (k*dte)^T: float2 loads, 4 elems/thread-iter
    #pragma unroll
    for (int it = 0; it < 8; ++it) {
        const int u = it * 256 + tid;              // 0..2047
        const int d = (u & 63) * 2, i = (u >> 6) * 2;   // d even, i even (wave-uniform i)
        const float dte0 = __shfl(dte_own, i, 64);
        const float dte1 = __shfl(dte_own, i + 1, 64);
        const float2 va = *(const float2*)(v + base + (size_t)i * Dp + d);
        const float2 vb = *(const float2*)(v + base + (size_t)(i + 1) * Dp + d);
        const float2 ka = *(const float2*)(k + base + (size_t)i * Dp + d);
        const float2 kb = *(const float2*)(k + base + (size_t)(i + 1) * Dp + d);
        *(unsigned*)&s_vt[d * STR + i]       = pack2(va.x, vb.x);
        *(unsigned*)&s_vt[(d + 1) * STR + i] = pack2(va.y, vb.y);
        *(unsigned*)&s_kt[d * STR + i]       = pack2(ka.x * dte0, kb.x * dte1);
        *(unsigned*)&s_kt[(d + 1) * STR + i] = pack2(ka.y * dte0, kb.y * dte1);
    }

    // q B-fragments straight from global (wave-exclusive rows 16w..16w+15)
    bf16x8 qf[4];
    {
        const float* qrow = q + base + (size_t)(16 * w + m16) * Dp + quad * 8;
        #pragma unroll
        for (int ks = 0; ks < 4; ++ks) {
            const float4 a = *(const float4*)(qrow + ks * 32);
            const float4 b = *(const float4*)(qrow + ks * 32 + 4);
            union { bf16x8 v; unsigned ui[4]; } t;
            t.ui[0] = pack2(a.x, a.y); t.ui[1] = pack2(a.z, a.w);
            t.ui[2] = pack2(b.x, b.y); t.ui[3] = pack2(b.z, b.w);
            qf[ks] = t.v;
        }
    }

    // ---- GEMM1 swapped: accP[nt] = C[j][i], j = 16nt+4q+r, i = 16w+m16.
    //      A = k rows j loaded straight from global; triangular skip nt<=w ----
    f32x4 accP[4] = {};
    #pragma unroll
    for (int nt = 0; nt < 4; ++nt) {
        if (nt <= w) {
            const float* krow = k + base + (size_t)(16 * nt + m16) * Dp + quad * 8;
            float4 ra[4], rb[4];
            #pragma unroll
            for (int ks = 0; ks < 4; ++ks) {
                ra[ks] = *(const float4*)(krow + ks * 32);
                rb[ks] = *(const float4*)(krow + ks * 32 + 4);
            }
            #pragma unroll
            for (int ks = 0; ks < 4; ++ks) {
                union { bf16x8 v; unsigned ui[4]; } t;
                t.ui[0] = pack2(ra[ks].x, ra[ks].y); t.ui[1] = pack2(ra[ks].z, ra[ks].w);
                t.ui[2] = pack2(rb[ks].x, rb[ks].y); t.ui[3] = pack2(rb[ks].z, rb[ks].w);
                accP[nt] = MFMA(t.v, qf[ks], accP[nt]);
            }
        }
    }

    // ---- epilogue: mask + decay in registers, pack to bf16 pairs ----
    const float ci = __shfl(x, 16 * w + m16, 64);
    unsigned p_pk[4][2];
    #pragma unroll
    for (int nt = 0; nt < 4; ++nt) { p_pk[nt][0] = 0u; p_pk[nt][1] = 0u; }
    #pragma unroll
    for (int nt = 0; nt < 4; ++nt) {
        if (nt <= w) {
            float pm[4];
            #pragma unroll
            for (int r = 0; r < 4; ++r) {
                const int j = 16 * nt + 4 * quad + r;
                const float cj = __shfl(x, j, 64);
                float val = accP[nt][r] * expf(ci - cj);
                if (nt == w) val = (16 * w + m16 >= j) ? val : 0.f;  // mask only on diagonal tile
                pm[r] = val;
            }
            p_pk[nt][0] = pack2(pm[0], pm[1]);
            p_pk[nt][1] = pack2(pm[2], pm[3]);
        }
    }

    // ---- in-register transpose: build GEMM2 B-frags af[ks] = P rows i over K=j.
    //  word m of target quad q' = P[i][j0,j0+1], j0 = q'*8+ks*32+2m.
    //  source lane = (m16, 2*(q'&1) + (m>>1)); source reg nt = 2ks + (q'>>1). ----
    bf16x8 af[2];
    #pragma unroll
    for (int ks = 0; ks < 2; ++ks) {
        if (ks <= (w >> 1)) {
            union { bf16x8 v; unsigned ui[4]; } t;
            #pragma unroll
            for (int m = 0; m < 4; ++m) {
                const int src = m16 + 16 * (2 * (quad & 1) + (m >> 1));
                const unsigned aA = (unsigned)__shfl((int)p_pk[2 * ks][m & 1], src, 64);
                const unsigned aB = (unsigned)__shfl((int)p_pk[2 * ks + 1][m & 1], src, 64);
                t.ui[m] = (quad >> 1) ? aB : aA;
            }
            af[ks] = t.v;
        }
    }

    __syncthreads();   // s_vt/s_kt staged (the only barrier)

    // ---- GEMM3 swapped: C[d][e] = sum_i (k*dte)[i][d] * v[i][e].
    //      A = s_kt rows d (8 tiles), B = s_vt rows e (wave-exclusive tiles 2w,2w+1).
    //      Store uint2: 4 consecutive d per lane at ub[e*128 + d0]. ----
    {
        f32x4 accU[2][8] = {};
        #pragma unroll
        for (int ks = 0; ks < 2; ++ks) {
            const bf16x8 b0 = *(const bf16x8*)&s_vt[(16 * (2 * w)     + m16) * STR + quad * 8 + ks * 32];
            const bf16x8 b1 = *(const bf16x8*)&s_vt[(16 * (2 * w + 1) + m16) * STR + quad * 8 + ks * 32];
            #pragma unroll
            for (int nt = 0; nt < 8; ++nt) {
                const bf16x8 a = *(const bf16x8*)&s_kt[(16 * nt + m16) * STR + quad * 8 + ks * 32];
                accU[0][nt] = MFMA(a, b0, accU[0][nt]);
                accU[1][nt] = MFMA(a, b1, accU[1][nt]);
            }
        }
        unsigned short* ub = upd + (size_t)blk * Dp * Dp;
        #pragma unroll
        for (int mt = 0; mt < 2; ++mt) {
            const int e = 16 * (2 * w + mt) + m16;
            #pragma unroll
            for (int nt = 0; nt < 8; ++nt) {
                uint2 pw;
                pw.x = pack2(accU[mt][nt][0], accU[mt][nt][1]);
                pw.y = pack2(accU[mt][nt][2], accU[mt][nt][3]);
                *(uint2*)&ub[(size_t)e * Dp + 16 * nt + 4 * quad] = pw;
            }
        }
    }

    // ---- GEMM2 swapped: out_intra[i][d]; C[d][i] = sum_j v[j][d] * P[i][j].
    //      A = s_vt rows d (8 tiles), B = af (P rows i).  float4 stores. ----
    {
        f32x4 accO[8] = {};
        #pragma unroll
        for (int ks = 0; ks < 2; ++ks) {
            if (ks <= (w >> 1)) {      // waves 0,1: j<32 suffices (P masked above i)
                #pragma unroll
                for (int nt = 0; nt < 8; ++nt) {
                    const bf16x8 a = *(const bf16x8*)&s_vt[(16 * nt + m16) * STR + quad * 8 + ks * 32];
                    accO[nt] = MFMA(a, af[ks], accO[nt]);
                }
            }
        }
        const int i = 16 * w + m16;
        #pragma unroll
        for (int nt = 0; nt < 8; ++nt) {
            float4 st;
            st.x = accO[nt][0]; st.y = accO[nt][1];
            st.z = accO[nt][2]; st.w = accO[nt][3];
            *(float4*)&out[base + (size_t)i * Dp + 16 * nt + 4 * quad] = st;
        }
    }
}

// ---------------------------------------------------------------------------
// Kernel B: sequential inter-chunk scan over bf16 states, fp32 accumulation.
// uint4 (8 bf16) per thread per chunk, depth-4 prefetch. In-place: slot c is
// read (updT_c) then overwritten with the PRE-chunk state.
// 512 blocks (32g x 16 slabs) x 128 threads.
// ---------------------------------------------------------------------------
__global__ __launch_bounds__(128) void gdn_scan(
    unsigned short* __restrict__ upd, const float* __restrict__ tot_buf)
{
    const int g = blockIdx.x >> 4, slab = blockIdx.x & 15, tid = threadIdx.x;
    __shared__ float s_e[NCp];
    if (tid < NCp) s_e[tid] = expf(tot_buf[g * NCp + tid]);
    __syncthreads();
    // per chunk-state: 16384 bf16 = 2048 uint4; chunk stride = 2048 uint4
    uint4* b = (uint4*)(upd + (size_t)g * NCp * Dp * Dp) + slab * 128 + tid;
    float s0 = 0.f, s1 = 0.f, s2 = 0.f, s3 = 0.f;
    float s4 = 0.f, s5 = 0.f, s6 = 0.f, s7 = 0.f;
    uint4 pf[4];
    #pragma unroll
    for (int j = 0; j < 4; ++j) pf[j] = b[(size_t)j * 2048];
    #pragma unroll
    for (int cc = 0; cc < NCp; ++cc) {
        const uint4 cur = pf[cc & 3];
        if (cc + 4 < NCp) pf[cc & 3] = b[(size_t)(cc + 4) * 2048];
        const float e = s_e[cc];
        uint4 stq;
        stq.x = pack2(s0, s1); stq.y = pack2(s2, s3);
        stq.z = pack2(s4, s5); stq.w = pack2(s6, s7);
        b[(size_t)cc * 2048] = stq;
        s0 = s0 * e + bflo(cur.x); s1 = s1 * e + bfhi(cur.x);
        s2 = s2 * e + bflo(cur.y); s3 = s3 * e + bfhi(cur.y);
        s4 = s4 * e + bflo(cur.z); s5 = s5 * e + bfhi(cur.z);
        s6 = s6 * e + bflo(cur.w); s7 = s7 * e + bfhi(cur.w);
    }
}

// ---------------------------------------------------------------------------
// Kernel C: out[i][e] += dfs[i] * sum_d q[i][d] * S_c[d][e].  Zero LDS.
// out-tile (+= operand) preloaded BEFORE the MFMA loop; state B-frags read
// straight from global in batches of 8 so loads stay in flight.
// ---------------------------------------------------------------------------
__global__ __launch_bounds__(256) void gdn_inter(
    const float* __restrict__ q, const unsigned short* __restrict__ state,
    const float* __restrict__ dfs_buf, float* __restrict__ out)
{
    const int blk = blockIdx.x, g = blk >> 6, c = blk & 63;
    const int tid = threadIdx.x, lane = tid & 63, w = tid >> 6;
    const int m16 = lane & 15, quad = lane >> 4;
    const size_t base  = ((size_t)g * Sp + (size_t)c * BTp) * Dp;
    const size_t bbase = (size_t)g * Sp + (size_t)c * BTp;
    const unsigned short* sb = state + (size_t)blk * Dp * Dp;
    const int i0 = 16 * w + quad * 4;

    const float scale = dfs_buf[bbase + 16 * w + m16];
    bf16x8 qf[4];
    const float* qrow = q + base + (size_t)(16 * w + m16) * Dp + quad * 8;
    #pragma unroll
    for (int ks = 0; ks < 4; ++ks) {
        const float4 a = *(const float4*)(qrow + ks * 32);
        const float4 b = *(const float4*)(qrow + ks * 32 + 4);
        union { bf16x8 v; unsigned ui[4]; } t;
        t.ui[0] = pack2(a.x * scale, a.y * scale);
        t.ui[1] = pack2(a.z * scale, a.w * scale);
        t.ui[2] = pack2(b.x * scale, b.y * scale);
        t.ui[3] = pack2(b.w * scale, b.w * scale);  // placeholder (overwritten below)
        t.ui[3] = pack2(b.z * scale, b.w * scale);
        qf[ks] = t.v;
    }

    // preload the += operand while MFMAs run
    float ov[8][4];
    #pragma unroll
    for (int nt = 0; nt < 8; ++nt)
        #pragma unroll
        for (int r = 0; r < 4; ++r)
            ov[nt][r] = out[base + (size_t)(i0 + r) * Dp + 16 * nt + m16];

    f32x4 acc[8] = {};
    #pragma unroll
    for (int ks = 0; ks < 4; ++ks) {
        bf16x8 bfr[8];
        #pragma unroll
        for (int nt = 0; nt < 8; ++nt)
            bfr[nt] = *(const bf16x8*)(sb + (16 * nt + m16) * Dp + quad * 8 + ks * 32);
        #pragma unroll
        for (int nt = 0; nt < 8; ++nt)
            acc[nt] = MFMA(qf[ks], bfr[nt], acc[nt]);
    }
    #pragma unroll
    for (int nt = 0; nt < 8; ++nt) {
        const int e = 16 * nt + m16;
        #pragma unroll
        for (int r = 0; r < 4; ++r)
            out[base + (size_t)(i0 + r) * Dp + e] = ov[nt][r] + acc[nt][r];
    }
}

// ---------------------------------------------------------------------------
extern "C" void kernel_launch(void* const* d_in, const int* in_sizes, int n_in,
                              void* d_out, int out_size, void* d_ws, size_t ws_size,
                              hipStream_t stream) {
    const float* q    = (const float*)d_in[0];
    const float* k    = (const float*)d_in[1];
    const float* v    = (const float*)d_in[2];
    const float* beta = (const float*)d_in[3];
    float* out = (float*)d_out;

    unsigned short* upd = (unsigned short*)d_ws;             // G*NC*D*D bf16 (updT/stateT)
    float* tot_buf = (float*)(upd + (size_t)Gp * NCp * Dp * Dp);
    float* dfs_buf = tot_buf + Gp * NCp;

    gdn_intra<<<Gp * NCp, 256, 0, stream>>>(q, k, v, beta, out, upd, tot_buf, dfs_buf);
    gdn_scan <<<Gp * 16, 128, 0, stream>>>(upd, tot_buf);
    gdn_inter<<<Gp * NCp, 256, 0, stream>>>(q, upd, dfs_buf, out);
}

// Round 2
// 315.631 us; speedup vs baseline: 1.0160x; 1.0160x over previous
//
#include <hip/hip_runtime.h>
#include <hip/hip_bf16.h>
#include <math.h>

// Problem constants: B=4,H=8,S=4096,D=128,BT=64
#define Gp  32      // B*H
#define Sp  4096
#define Dp  128
#define BTp 64
#define NCp 64      // S/BT

typedef __attribute__((ext_vector_type(8))) short bf16x8;
typedef __attribute__((ext_vector_type(4))) float f32x4;

#define MFMA(a,b,c) __builtin_amdgcn_mfma_f32_16x16x32_bf16((a),(b),(c),0,0,0)

// XOR swizzle for [128][64] bf16 transposed tiles: elem (d,i) at
//   d*64 + (((i>>3) ^ ((d&15)>>1)) << 3) + (i&7)
// reads (row d fixed, 8 consecutive i) and 8-row uint4 writes are conflict-free.
#define TSWZ(d, slot) ((((slot) ^ (((d) & 15) >> 1)) << 3))

__device__ inline unsigned pack2(float lo, float hi) {
    __hip_bfloat162 h = __float22bfloat162_rn(make_float2(lo, hi));  // v_cvt_pk_bf16_f32
    union { __hip_bfloat162 v; unsigned u; } t; t.v = h; return t.u;
}
__device__ inline float bflo(unsigned u) { union { unsigned u; float f; } t; t.u = u << 16; return t.f; }
__device__ inline float bfhi(unsigned u) { union { unsigned u; float f; } t; t.u = u & 0xffff0000u; return t.f; }

// ---------------------------------------------------------------------------
// Kernel A: intra-chunk output + transposed per-chunk state term (updT, bf16).
// 256 threads, LDS = 48 KB -> 3 blocks/CU.  ONE barrier.
// GEMM1 swapped (A = k rows from s_k, B = q): lane holds P[j][i]; triangular
// tile skip.  P transposed to GEMM2 B-frags fully in-register (quad shuffles).
// GEMM3/GEMM2 swapped so stores vectorize (uint2 / float4).
// ---------------------------------------------------------------------------
__global__ __launch_bounds__(256, 3) void gdn_intra(
    const float* __restrict__ q, const float* __restrict__ k,
    const float* __restrict__ v, const float* __restrict__ beta,
    float* __restrict__ out, unsigned short* __restrict__ upd,
    float* __restrict__ tot_buf, float* __restrict__ dfs_buf)
{
    __shared__ unsigned short s_k [64 * 128];   // raw k, XOR-swizzled (row-major)
    __shared__ unsigned short s_vt[128 * 64];   // v^T  [d][i], TSWZ
    __shared__ unsigned short s_kt[128 * 64];   // (k*dte)^T [d][i], TSWZ

    const int blk = blockIdx.x, g = blk >> 6, c = blk & 63;
    const int tid = threadIdx.x, lane = tid & 63, w = tid >> 6;
    const int m16 = lane & 15, quad = lane >> 4;
    const size_t base  = ((size_t)g * Sp + (size_t)c * BTp) * Dp;
    const size_t bbase = (size_t)g * Sp + (size_t)c * BTp;

    // every wave redundantly computes the 64-lane log-beta prefix (no LDS dep)
    float x = logf(beta[bbase + lane] + 1e-6f);
    #pragma unroll
    for (int off = 1; off < 64; off <<= 1) {
        float n = __shfl_up(x, off, 64);
        if (lane >= off) x += n;
    }
    const float tot = __shfl(x, 63, 64);
    const float dte_own = expf(tot - x);          // lane L holds dte[L]
    if (tid < 64) dfs_buf[bbase + lane] = expf(x);
    if (tid == 63) tot_buf[g * NCp + c] = tot;

    // q B-fragments straight from global (wave-exclusive rows 16w..16w+15)
    bf16x8 qf[4];
    {
        const float* qrow = q + base + (size_t)(16 * w + m16) * Dp + quad * 8;
        #pragma unroll
        for (int ks = 0; ks < 4; ++ks) {
            const float4 a = *(const float4*)(qrow + ks * 32);
            const float4 b = *(const float4*)(qrow + ks * 32 + 4);
            union { bf16x8 v; unsigned ui[4]; } t;
            t.ui[0] = pack2(a.x, a.y); t.ui[1] = pack2(a.z, a.w);
            t.ui[2] = pack2(b.x, b.y); t.ui[3] = pack2(b.z, b.w);
            qf[ks] = t.v;
        }
    }

    // stage k -> s_k (swizzled): float4 loads, 8B LDS writes (conflict-free-ish)
    #pragma unroll
    for (int it = 0; it < 8; ++it) {
        const int idx = (it * 256 + tid) * 4;      // elem 0..8191, mult of 4
        const int i = idx >> 7, d = idx & 127;     // d multiple of 4
        const float4 kv = *(const float4*)(k + base + (size_t)i * Dp + d);
        const int ad = i * 128 + (((d >> 3) ^ (i & 15)) << 3) + (d & 7);
        uint2 pw; pw.x = pack2(kv.x, kv.y); pw.y = pack2(kv.z, kv.w);
        *(uint2*)&s_k[ad] = pw;
    }

    // stage v^T and (k*dte)^T: 8-row column slices, uint4 writes (conflict-free)
    #pragma unroll
    for (int it = 0; it < 2; ++it) {
        const int dd = 2 * (tid & 63);             // even col 0..126
        const int i  = 32 * it + 8 * w;            // wave-uniform 8-row base
        float2 lv[8], lk[8];
        #pragma unroll
        for (int r = 0; r < 8; ++r) {
            lv[r] = *(const float2*)(v + base + (size_t)(i + r) * Dp + dd);
            lk[r] = *(const float2*)(k + base + (size_t)(i + r) * Dp + dd);
        }
        float dt[8];
        #pragma unroll
        for (int r = 0; r < 8; ++r) dt[r] = __shfl(dte_own, i + r, 64);
        const int sl = TSWZ(dd, i >> 3);           // same for col dd+1 (dd even)
        uint4 t0, t1;
        t0.x = pack2(lv[0].x, lv[1].x); t0.y = pack2(lv[2].x, lv[3].x);
        t0.z = pack2(lv[4].x, lv[5].x); t0.w = pack2(lv[6].x, lv[7].x);
        t1.x = pack2(lv[0].y, lv[1].y); t1.y = pack2(lv[2].y, lv[3].y);
        t1.z = pack2(lv[4].y, lv[5].y); t1.w = pack2(lv[6].y, lv[7].y);
        *(uint4*)&s_vt[dd * 64 + sl]       = t0;
        *(uint4*)&s_vt[(dd + 1) * 64 + sl] = t1;
        t0.x = pack2(lk[0].x * dt[0], lk[1].x * dt[1]); t0.y = pack2(lk[2].x * dt[2], lk[3].x * dt[3]);
        t0.z = pack2(lk[4].x * dt[4], lk[5].x * dt[5]); t0.w = pack2(lk[6].x * dt[6], lk[7].x * dt[7]);
        t1.x = pack2(lk[0].y * dt[0], lk[1].y * dt[1]); t1.y = pack2(lk[2].y * dt[2], lk[3].y * dt[3]);
        t1.z = pack2(lk[4].y * dt[4], lk[5].y * dt[5]); t1.w = pack2(lk[6].y * dt[6], lk[7].y * dt[7]);
        *(uint4*)&s_kt[dd * 64 + sl]       = t0;
        *(uint4*)&s_kt[(dd + 1) * 64 + sl] = t1;
    }

    __syncthreads();   // the only barrier

    // ---- GEMM1 swapped: accP[nt] = C[j][i], j = 16nt+4quad+r, i = 16w+m16.
    //      A = k rows j from s_k (swizzled); triangular skip nt <= w ----
    f32x4 accP[4] = {};
    #pragma unroll
    for (int nt = 0; nt < 4; ++nt) {
        if (nt <= w) {
            #pragma unroll
            for (int ks = 0; ks < 4; ++ks) {
                const bf16x8 kf = *(const bf16x8*)&s_k[(16 * nt + m16) * 128 + (((quad + 4 * ks) ^ m16) << 3)];
                accP[nt] = MFMA(kf, qf[ks], accP[nt]);
            }
        }
    }

    // ---- epilogue: mask + decay in registers, pack to bf16 pairs ----
    const float ci = __shfl(x, 16 * w + m16, 64);
    unsigned p_pk[4][2];
    #pragma unroll
    for (int nt = 0; nt < 4; ++nt) { p_pk[nt][0] = 0u; p_pk[nt][1] = 0u; }
    #pragma unroll
    for (int nt = 0; nt < 4; ++nt) {
        if (nt <= w) {
            float pm[4];
            #pragma unroll
            for (int r = 0; r < 4; ++r) {
                const int j = 16 * nt + 4 * quad + r;
                const float cj = __shfl(x, j, 64);
                float val = accP[nt][r] * expf(ci - cj);
                if (nt == w) val = (16 * w + m16 >= j) ? val : 0.f;  // mask only on diagonal tile
                pm[r] = val;
            }
            p_pk[nt][0] = pack2(pm[0], pm[1]);
            p_pk[nt][1] = pack2(pm[2], pm[3]);
        }
    }

    // ---- in-register transpose: build GEMM2 B-frags af[ks] = P rows i over K=j.
    //  word m of target quad q' = P[i][j0,j0+1], j0 = q'*8+ks*32+2m.
    //  source lane = (m16, 2*(q'&1) + (m>>1)); source reg nt = 2ks + (q'>>1). ----
    bf16x8 af[2];
    #pragma unroll
    for (int ks = 0; ks < 2; ++ks) {
        if (ks <= (w >> 1)) {
            union { bf16x8 v; unsigned ui[4]; } t;
            #pragma unroll
            for (int m = 0; m < 4; ++m) {
                const int src = m16 + 16 * (2 * (quad & 1) + (m >> 1));
                const unsigned aA = (unsigned)__shfl((int)p_pk[2 * ks][m & 1], src, 64);
                const unsigned aB = (unsigned)__shfl((int)p_pk[2 * ks + 1][m & 1], src, 64);
                t.ui[m] = (quad >> 1) ? aB : aA;
            }
            af[ks] = t.v;
        }
    }

    // ---- GEMM3 swapped: C[d][e] = sum_i (k*dte)[i][d] * v[i][e].
    //      A = s_kt rows d (8 tiles), B = s_vt rows e (wave-exclusive tiles 2w,2w+1).
    //      Store uint2: 4 consecutive d per lane at ub[e*128 + d0]. ----
    {
        f32x4 accU[2][8] = {};
        #pragma unroll
        for (int ks = 0; ks < 2; ++ks) {
            const int sw = TSWZ(m16, quad + 4 * ks);   // (d&15)=m16 for all rows used
            const bf16x8 b0 = *(const bf16x8*)&s_vt[(16 * (2 * w)     + m16) * 64 + sw];
            const bf16x8 b1 = *(const bf16x8*)&s_vt[(16 * (2 * w + 1) + m16) * 64 + sw];
            #pragma unroll
            for (int nt = 0; nt < 8; ++nt) {
                const bf16x8 a = *(const bf16x8*)&s_kt[(16 * nt + m16) * 64 + sw];
                accU[0][nt] = MFMA(a, b0, accU[0][nt]);
                accU[1][nt] = MFMA(a, b1, accU[1][nt]);
            }
        }
        unsigned short* ub = upd + (size_t)blk * Dp * Dp;
        #pragma unroll
        for (int mt = 0; mt < 2; ++mt) {
            const int e = 16 * (2 * w + mt) + m16;
            #pragma unroll
            for (int nt = 0; nt < 8; ++nt) {
                uint2 pw;
                pw.x = pack2(accU[mt][nt][0], accU[mt][nt][1]);
                pw.y = pack2(accU[mt][nt][2], accU[mt][nt][3]);
                *(uint2*)&ub[(size_t)e * Dp + 16 * nt + 4 * quad] = pw;
            }
        }
    }

    // ---- GEMM2 swapped: out_intra[i][d]; C[d][i] = sum_j v[j][d] * P[i][j].
    //      A = s_vt rows d (8 tiles), B = af (P rows i).  float4 stores. ----
    {
        f32x4 accO[8] = {};
        #pragma unroll
        for (int ks = 0; ks < 2; ++ks) {
            if (ks <= (w >> 1)) {      // waves 0,1: j<32 suffices (P masked above i)
                const int sw = TSWZ(m16, quad + 4 * ks);
                #pragma unroll
                for (int nt = 0; nt < 8; ++nt) {
                    const bf16x8 a = *(const bf16x8*)&s_vt[(16 * nt + m16) * 64 + sw];
                    accO[nt] = MFMA(a, af[ks], accO[nt]);
                }
            }
        }
        const int i = 16 * w + m16;
        #pragma unroll
        for (int nt = 0; nt < 8; ++nt) {
            float4 st;
            st.x = accO[nt][0]; st.y = accO[nt][1];
            st.z = accO[nt][2]; st.w = accO[nt][3];
            *(float4*)&out[base + (size_t)i * Dp + 16 * nt + 4 * quad] = st;
        }
    }
}

// ---------------------------------------------------------------------------
// Kernel B: sequential inter-chunk scan over bf16 states, fp32 accumulation.
// uint4 (8 bf16) per thread per chunk, depth-4 prefetch. In-place: slot c is
// read (updT_c) then overwritten with the PRE-chunk state.
// 512 blocks (32g x 16 slabs) x 128 threads.
// ---------------------------------------------------------------------------
__global__ __launch_bounds__(128) void gdn_scan(
    unsigned short* __restrict__ upd, const float* __restrict__ tot_buf)
{
    const int g = blockIdx.x >> 4, slab = blockIdx.x & 15, tid = threadIdx.x;
    __shared__ float s_e[NCp];
    if (tid < NCp) s_e[tid] = expf(tot_buf[g * NCp + tid]);
    __syncthreads();
    // per chunk-state: 16384 bf16 = 2048 uint4; chunk stride = 2048 uint4
    uint4* b = (uint4*)(upd + (size_t)g * NCp * Dp * Dp) + slab * 128 + tid;
    float s0 = 0.f, s1 = 0.f, s2 = 0.f, s3 = 0.f;
    float s4 = 0.f, s5 = 0.f, s6 = 0.f, s7 = 0.f;
    uint4 pf[4];
    #pragma unroll
    for (int j = 0; j < 4; ++j) pf[j] = b[(size_t)j * 2048];
    #pragma unroll
    for (int cc = 0; cc < NCp; ++cc) {
        const uint4 cur = pf[cc & 3];
        if (cc + 4 < NCp) pf[cc & 3] = b[(size_t)(cc + 4) * 2048];
        const float e = s_e[cc];
        uint4 stq;
        stq.x = pack2(s0, s1); stq.y = pack2(s2, s3);
        stq.z = pack2(s4, s5); stq.w = pack2(s6, s7);
        b[(size_t)cc * 2048] = stq;
        s0 = s0 * e + bflo(cur.x); s1 = s1 * e + bfhi(cur.x);
        s2 = s2 * e + bflo(cur.y); s3 = s3 * e + bfhi(cur.y);
        s4 = s4 * e + bflo(cur.z); s5 = s5 * e + bfhi(cur.z);
        s6 = s6 * e + bflo(cur.w); s7 = s7 * e + bfhi(cur.w);
    }
}

// ---------------------------------------------------------------------------
// Kernel C: out[i][e] += dfs[i] * sum_d q[i][d] * S_c[d][e].  Zero LDS.
// Swapped MFMA (A = stateT rows e, B = q rows i) -> C[e][i]: the += operand
// preload and the final store are float4 (8 ops each instead of 32 scalar).
// ---------------------------------------------------------------------------
__global__ __launch_bounds__(256) void gdn_inter(
    const float* __restrict__ q, const unsigned short* __restrict__ state,
    const float* __restrict__ dfs_buf, float* __restrict__ out)
{
    const int blk = blockIdx.x, g = blk >> 6, c = blk & 63;
    const int tid = threadIdx.x, lane = tid & 63, w = tid >> 6;
    const int m16 = lane & 15, quad = lane >> 4;
    const size_t base  = ((size_t)g * Sp + (size_t)c * BTp) * Dp;
    const size_t bbase = (size_t)g * Sp + (size_t)c * BTp;
    const unsigned short* sb = state + (size_t)blk * Dp * Dp;
    const int i = 16 * w + m16;                    // this lane's output row

    const float scale = dfs_buf[bbase + i];
    bf16x8 qf[4];
    const float* qrow = q + base + (size_t)i * Dp + quad * 8;
    #pragma unroll
    for (int ks = 0; ks < 4; ++ks) {
        const float4 a = *(const float4*)(qrow + ks * 32);
        const float4 b = *(const float4*)(qrow + ks * 32 + 4);
        union { bf16x8 v; unsigned ui[4]; } t;
        t.ui[0] = pack2(a.x * scale, a.y * scale);
        t.ui[1] = pack2(a.z * scale, a.w * scale);
        t.ui[2] = pack2(b.x * scale, b.y * scale);
        t.ui[3] = pack2(b.z * scale, b.w * scale);
        qf[ks] = t.v;
    }

    // preload the += operand (float4) while MFMAs run
    float4 ov[8];
    #pragma unroll
    for (int nt = 0; nt < 8; ++nt)
        ov[nt] = *(const float4*)&out[base + (size_t)i * Dp + 16 * nt + 4 * quad];

    f32x4 acc[8] = {};
    #pragma unroll
    for (int ks = 0; ks < 4; ++ks) {
        bf16x8 afr[8];
        #pragma unroll
        for (int nt = 0; nt < 8; ++nt)
            afr[nt] = *(const bf16x8*)(sb + (16 * nt + m16) * Dp + quad * 8 + ks * 32);
        #pragma unroll
        for (int nt = 0; nt < 8; ++nt)
            acc[nt] = MFMA(afr[nt], qf[ks], acc[nt]);   // C[e][i]
    }
    #pragma unroll
    for (int nt = 0; nt < 8; ++nt) {
        float4 st;
        st.x = ov[nt].x + acc[nt][0]; st.y = ov[nt].y + acc[nt][1];
        st.z = ov[nt].z + acc[nt][2]; st.w = ov[nt].w + acc[nt][3];
        *(float4*)&out[base + (size_t)i * Dp + 16 * nt + 4 * quad] = st;
    }
}

// ---------------------------------------------------------------------------
extern "C" void kernel_launch(void* const* d_in, const int* in_sizes, int n_in,
                              void* d_out, int out_size, void* d_ws, size_t ws_size,
                              hipStream_t stream) {
    const float* q    = (const float*)d_in[0];
    const float* k    = (const float*)d_in[1];
    const float* v    = (const float*)d_in[2];
    const float* beta = (const float*)d_in[3];
    float* out = (float*)d_out;

    unsigned short* upd = (unsigned short*)d_ws;             // G*NC*D*D bf16 (updT/stateT)
    float* tot_buf = (float*)(upd + (size_t)Gp * NCp * Dp * Dp);
    float* dfs_buf = tot_buf + Gp * NCp;

    gdn_intra<<<Gp * NCp, 256, 0, stream>>>(q, k, v, beta, out, upd, tot_buf, dfs_buf);
    gdn_scan <<<Gp * 16, 128, 0, stream>>>(upd, tot_buf);
    gdn_inter<<<Gp * NCp, 256, 0, stream>>>(q, upd, dfs_buf, out);
}

// Round 3
// 302.055 us; speedup vs baseline: 1.0617x; 1.0449x over previous
//
#include <hip/hip_runtime.h>
#include <hip/hip_bf16.h>
#include <math.h>

// Problem constants: B=4,H=8,S=4096,D=128,BT=64
#define Gp  32      // B*H
#define Sp  4096
#define Dp  128
#define BTp 64
#define NCp 64      // S/BT

typedef __attribute__((ext_vector_type(8))) short bf16x8;
typedef __attribute__((ext_vector_type(4))) float f32x4;

#define MFMA(a,b,c) __builtin_amdgcn_mfma_f32_16x16x32_bf16((a),(b),(c),0,0,0)

// XOR swizzle for [128][64] bf16 transposed tiles: elem (d,i) at
//   d*64 + (((i>>3) ^ (((d&15)>>1))) << 3) + (i&7)
#define TSWZ(d, slot) ((((slot) ^ (((d) & 15) >> 1)) << 3))

__device__ inline unsigned pack2(float lo, float hi) {
    __hip_bfloat162 h = __float22bfloat162_rn(make_float2(lo, hi));  // v_cvt_pk_bf16_f32
    union { __hip_bfloat162 v; unsigned u; } t; t.v = h; return t.u;
}
__device__ inline float bflo(unsigned u) { union { unsigned u; float f; } t; t.u = u << 16; return t.f; }
__device__ inline float bfhi(unsigned u) { union { unsigned u; float f; } t; t.u = u & 0xffff0000u; return t.f; }

// ---------------------------------------------------------------------------
// Kernel 0: per-chunk beta statistics (cum log-beta, exp decays, totals).
// One wave per chunk; removes the logf + 6-deep shfl chain from the 2048
// intra blocks' critical path.  512 blocks x 256 threads.
// ---------------------------------------------------------------------------
__global__ __launch_bounds__(256) void gdn_beta(
    const float* __restrict__ beta, float* __restrict__ cum_buf,
    float* __restrict__ dte_buf, float* __restrict__ dfs_buf,
    float* __restrict__ tot_buf)
{
    const int tid = threadIdx.x, lane = tid & 63, w = tid >> 6;
    const int cc = blockIdx.x * 4 + w;             // global chunk id
    const int g = cc >> 6, c = cc & 63;
    const size_t bbase = (size_t)g * Sp + (size_t)c * BTp;
    float x = logf(beta[bbase + lane] + 1e-6f);
    #pragma unroll
    for (int off = 1; off < 64; off <<= 1) {
        float n = __shfl_up(x, off, 64);
        if (lane >= off) x += n;
    }
    const float tot = __shfl(x, 63, 64);
    cum_buf[bbase + lane] = x;
    dfs_buf[bbase + lane] = expf(x);
    dte_buf[bbase + lane] = expf(tot - x);
    if (lane == 63) tot_buf[g * NCp + c] = tot;
}

// ---------------------------------------------------------------------------
// Kernel A: intra-chunk output + transposed per-chunk state term (updT, bf16).
// 256 threads, LDS = 48 KB -> 3 blocks/CU.  ONE barrier.
// All global loads issued up-front (no scan, no logf); one k load feeds both
// s_k (row-major) and s_kt (transposed).  out_intra stored bf16 when ws fits.
// ---------------------------------------------------------------------------
__global__ __launch_bounds__(256, 3) void gdn_intra(
    const float* __restrict__ q, const float* __restrict__ k,
    const float* __restrict__ v, const float* __restrict__ cum_buf,
    const float* __restrict__ dte_buf,
    float* __restrict__ out, unsigned short* __restrict__ outi,
    unsigned short* __restrict__ upd)
{
    __shared__ unsigned short s_k [64 * 128];   // raw k, XOR-swizzled (row-major)
    __shared__ unsigned short s_vt[128 * 64];   // v^T  [d][i], TSWZ
    __shared__ unsigned short s_kt[128 * 64];   // (k*dte)^T [d][i], TSWZ

    const int blk = blockIdx.x, g = blk >> 6, c = blk & 63;
    const int tid = threadIdx.x, lane = tid & 63, w = tid >> 6;
    const int m16 = lane & 15, quad = lane >> 4;
    const size_t base  = ((size_t)g * Sp + (size_t)c * BTp) * Dp;
    const size_t bbase = (size_t)g * Sp + (size_t)c * BTp;

    // ---- issue ALL global loads back-to-back ----
    const float x = cum_buf[bbase + lane];         // per-lane cum log-beta

    const int dd = 4 * (tid & 31);                 // col group (4 cols)
    const int rg = tid >> 5;                       // row group (8 rows)
    const int i0 = 8 * rg;
    const float* kp = k + base + (size_t)i0 * Dp + dd;
    const float* vp = v + base + (size_t)i0 * Dp + dd;
    float4 kx[8], vx[8];
    #pragma unroll
    for (int r = 0; r < 8; ++r) kx[r] = *(const float4*)(kp + (size_t)r * Dp);
    #pragma unroll
    for (int r = 0; r < 8; ++r) vx[r] = *(const float4*)(vp + (size_t)r * Dp);
    const float4 dt0 = *(const float4*)(dte_buf + bbase + i0);
    const float4 dt1 = *(const float4*)(dte_buf + bbase + i0 + 4);

    const float* qrow = q + base + (size_t)(16 * w + m16) * Dp + quad * 8;
    float4 qa[4], qb[4];
    #pragma unroll
    for (int ks = 0; ks < 4; ++ks) {
        qa[ks] = *(const float4*)(qrow + ks * 32);
        qb[ks] = *(const float4*)(qrow + ks * 32 + 4);
    }

    // ---- s_k: row-major swizzled, 8 uint2 writes from kx ----
    #pragma unroll
    for (int r = 0; r < 8; ++r) {
        const int i = i0 + r;
        const int ad = i * 128 + (((dd >> 3) ^ (i & 15)) << 3) + (dd & 7);
        uint2 pw; pw.x = pack2(kx[r].x, kx[r].y); pw.y = pack2(kx[r].z, kx[r].w);
        *(uint2*)&s_k[ad] = pw;
    }

    // ---- s_vt: 4 cols x 8 rows transposed pack, uint4 writes ----
    {
        uint4 t;
        t.x = pack2(vx[0].x, vx[1].x); t.y = pack2(vx[2].x, vx[3].x);
        t.z = pack2(vx[4].x, vx[5].x); t.w = pack2(vx[6].x, vx[7].x);
        *(uint4*)&s_vt[(dd + 0) * 64 + TSWZ(dd + 0, rg)] = t;
        t.x = pack2(vx[0].y, vx[1].y); t.y = pack2(vx[2].y, vx[3].y);
        t.z = pack2(vx[4].y, vx[5].y); t.w = pack2(vx[6].y, vx[7].y);
        *(uint4*)&s_vt[(dd + 1) * 64 + TSWZ(dd + 1, rg)] = t;
        t.x = pack2(vx[0].z, vx[1].z); t.y = pack2(vx[2].z, vx[3].z);
        t.z = pack2(vx[4].z, vx[5].z); t.w = pack2(vx[6].z, vx[7].z);
        *(uint4*)&s_vt[(dd + 2) * 64 + TSWZ(dd + 2, rg)] = t;
        t.x = pack2(vx[0].w, vx[1].w); t.y = pack2(vx[2].w, vx[3].w);
        t.z = pack2(vx[4].w, vx[5].w); t.w = pack2(vx[6].w, vx[7].w);
        *(uint4*)&s_vt[(dd + 3) * 64 + TSWZ(dd + 3, rg)] = t;
    }

    // ---- s_kt: same geometry, k scaled by dte[i] ----
    {
        const float d0 = dt0.x, d1 = dt0.y, d2 = dt0.z, d3 = dt0.w;
        const float d4 = dt1.x, d5 = dt1.y, d6 = dt1.z, d7 = dt1.w;
        uint4 t;
        t.x = pack2(kx[0].x * d0, kx[1].x * d1); t.y = pack2(kx[2].x * d2, kx[3].x * d3);
        t.z = pack2(kx[4].x * d4, kx[5].x * d5); t.w = pack2(kx[6].x * d6, kx[7].x * d7);
        *(uint4*)&s_kt[(dd + 0) * 64 + TSWZ(dd + 0, rg)] = t;
        t.x = pack2(kx[0].y * d0, kx[1].y * d1); t.y = pack2(kx[2].y * d2, kx[3].y * d3);
        t.z = pack2(kx[4].y * d4, kx[5].y * d5); t.w = pack2(kx[6].y * d6, kx[7].y * d7);
        *(uint4*)&s_kt[(dd + 1) * 64 + TSWZ(dd + 1, rg)] = t;
        t.x = pack2(kx[0].z * d0, kx[1].z * d1); t.y = pack2(kx[2].z * d2, kx[3].z * d3);
        t.z = pack2(kx[4].z * d4, kx[5].z * d5); t.w = pack2(kx[6].z * d6, kx[7].z * d7);
        *(uint4*)&s_kt[(dd + 2) * 64 + TSWZ(dd + 2, rg)] = t;
        t.x = pack2(kx[0].w * d0, kx[1].w * d1); t.y = pack2(kx[2].w * d2, kx[3].w * d3);
        t.z = pack2(kx[4].w * d4, kx[5].w * d5); t.w = pack2(kx[6].w * d6, kx[7].w * d7);
        *(uint4*)&s_kt[(dd + 3) * 64 + TSWZ(dd + 3, rg)] = t;
    }

    // ---- pack q fragments ----
    bf16x8 qf[4];
    #pragma unroll
    for (int ks = 0; ks < 4; ++ks) {
        union { bf16x8 v; unsigned ui[4]; } t;
        t.ui[0] = pack2(qa[ks].x, qa[ks].y); t.ui[1] = pack2(qa[ks].z, qa[ks].w);
        t.ui[2] = pack2(qb[ks].x, qb[ks].y); t.ui[3] = pack2(qb[ks].z, qb[ks].w);
        qf[ks] = t.v;
    }

    __syncthreads();   // the only barrier

    // ---- GEMM1 swapped: accP[nt] = C[j][i], j = 16nt+4quad+r, i = 16w+m16.
    //      A = k rows j from s_k (swizzled); triangular skip nt <= w ----
    f32x4 accP[4] = {};
    #pragma unroll
    for (int nt = 0; nt < 4; ++nt) {
        if (nt <= w) {
            #pragma unroll
            for (int ks = 0; ks < 4; ++ks) {
                const bf16x8 kf = *(const bf16x8*)&s_k[(16 * nt + m16) * 128 + (((quad + 4 * ks) ^ m16) << 3)];
                accP[nt] = MFMA(kf, qf[ks], accP[nt]);
            }
        }
    }

    // ---- epilogue: mask + decay in registers, pack to bf16 pairs ----
    const float ci = __shfl(x, 16 * w + m16, 64);
    unsigned p_pk[4][2];
    #pragma unroll
    for (int nt = 0; nt < 4; ++nt) { p_pk[nt][0] = 0u; p_pk[nt][1] = 0u; }
    #pragma unroll
    for (int nt = 0; nt < 4; ++nt) {
        if (nt <= w) {
            float pm[4];
            #pragma unroll
            for (int r = 0; r < 4; ++r) {
                const int j = 16 * nt + 4 * quad + r;
                const float cj = __shfl(x, j, 64);
                float val = accP[nt][r] * expf(ci - cj);
                if (nt == w) val = (16 * w + m16 >= j) ? val : 0.f;  // mask only on diagonal tile
                pm[r] = val;
            }
            p_pk[nt][0] = pack2(pm[0], pm[1]);
            p_pk[nt][1] = pack2(pm[2], pm[3]);
        }
    }

    // ---- in-register transpose: build GEMM2 B-frags af[ks] = P rows i over K=j ----
    bf16x8 af[2];
    #pragma unroll
    for (int ks = 0; ks < 2; ++ks) {
        if (ks <= (w >> 1)) {
            union { bf16x8 v; unsigned ui[4]; } t;
            #pragma unroll
            for (int m = 0; m < 4; ++m) {
                const int src = m16 + 16 * (2 * (quad & 1) + (m >> 1));
                const unsigned aA = (unsigned)__shfl((int)p_pk[2 * ks][m & 1], src, 64);
                const unsigned aB = (unsigned)__shfl((int)p_pk[2 * ks + 1][m & 1], src, 64);
                t.ui[m] = (quad >> 1) ? aB : aA;
            }
            af[ks] = t.v;
        }
    }

    // ---- GEMM3 swapped: C[d][e] = sum_i (k*dte)[i][d] * v[i][e] ----
    {
        f32x4 accU[2][8] = {};
        #pragma unroll
        for (int ks = 0; ks < 2; ++ks) {
            const int sw = TSWZ(m16, quad + 4 * ks);
            const bf16x8 b0 = *(const bf16x8*)&s_vt[(16 * (2 * w)     + m16) * 64 + sw];
            const bf16x8 b1 = *(const bf16x8*)&s_vt[(16 * (2 * w + 1) + m16) * 64 + sw];
            #pragma unroll
            for (int nt = 0; nt < 8; ++nt) {
                const bf16x8 a = *(const bf16x8*)&s_kt[(16 * nt + m16) * 64 + sw];
                accU[0][nt] = MFMA(a, b0, accU[0][nt]);
                accU[1][nt] = MFMA(a, b1, accU[1][nt]);
            }
        }
        unsigned short* ub = upd + (size_t)blk * Dp * Dp;
        #pragma unroll
        for (int mt = 0; mt < 2; ++mt) {
            const int e = 16 * (2 * w + mt) + m16;
            #pragma unroll
            for (int nt = 0; nt < 8; ++nt) {
                uint2 pw;
                pw.x = pack2(accU[mt][nt][0], accU[mt][nt][1]);
                pw.y = pack2(accU[mt][nt][2], accU[mt][nt][3]);
                *(uint2*)&ub[(size_t)e * Dp + 16 * nt + 4 * quad] = pw;
            }
        }
    }

    // ---- GEMM2 swapped: out_intra[i][d]; C[d][i] = sum_j v[j][d] * P[i][j] ----
    {
        f32x4 accO[8] = {};
        #pragma unroll
        for (int ks = 0; ks < 2; ++ks) {
            if (ks <= (w >> 1)) {      // waves 0,1: j<32 suffices (P masked above i)
                const int sw = TSWZ(m16, quad + 4 * ks);
                #pragma unroll
                for (int nt = 0; nt < 8; ++nt) {
                    const bf16x8 a = *(const bf16x8*)&s_vt[(16 * nt + m16) * 64 + sw];
                    accO[nt] = MFMA(a, af[ks], accO[nt]);
                }
            }
        }
        const int i = 16 * w + m16;
        if (outi) {
            #pragma unroll
            for (int nt = 0; nt < 8; ++nt) {
                uint2 pw;
                pw.x = pack2(accO[nt][0], accO[nt][1]);
                pw.y = pack2(accO[nt][2], accO[nt][3]);
                *(uint2*)&outi[base + (size_t)i * Dp + 16 * nt + 4 * quad] = pw;
            }
        } else {
            #pragma unroll
            for (int nt = 0; nt < 8; ++nt) {
                float4 st;
                st.x = accO[nt][0]; st.y = accO[nt][1];
                st.z = accO[nt][2]; st.w = accO[nt][3];
                *(float4*)&out[base + (size_t)i * Dp + 16 * nt + 4 * quad] = st;
            }
        }
    }
}

// ---------------------------------------------------------------------------
// Kernel B: sequential inter-chunk scan over bf16 states, fp32 accumulation.
// ---------------------------------------------------------------------------
__global__ __launch_bounds__(128) void gdn_scan(
    unsigned short* __restrict__ upd, const float* __restrict__ tot_buf)
{
    const int g = blockIdx.x >> 4, slab = blockIdx.x & 15, tid = threadIdx.x;
    __shared__ float s_e[NCp];
    if (tid < NCp) s_e[tid] = expf(tot_buf[g * NCp + tid]);
    __syncthreads();
    uint4* b = (uint4*)(upd + (size_t)g * NCp * Dp * Dp) + slab * 128 + tid;
    float s0 = 0.f, s1 = 0.f, s2 = 0.f, s3 = 0.f;
    float s4 = 0.f, s5 = 0.f, s6 = 0.f, s7 = 0.f;
    uint4 pf[4];
    #pragma unroll
    for (int j = 0; j < 4; ++j) pf[j] = b[(size_t)j * 2048];
    #pragma unroll
    for (int cc = 0; cc < NCp; ++cc) {
        const uint4 cur = pf[cc & 3];
        if (cc + 4 < NCp) pf[cc & 3] = b[(size_t)(cc + 4) * 2048];
        const float e = s_e[cc];
        uint4 stq;
        stq.x = pack2(s0, s1); stq.y = pack2(s2, s3);
        stq.z = pack2(s4, s5); stq.w = pack2(s6, s7);
        b[(size_t)cc * 2048] = stq;
        s0 = s0 * e + bflo(cur.x); s1 = s1 * e + bfhi(cur.x);
        s2 = s2 * e + bflo(cur.y); s3 = s3 * e + bfhi(cur.y);
        s4 = s4 * e + bflo(cur.z); s5 = s5 * e + bfhi(cur.z);
        s6 = s6 * e + bflo(cur.w); s7 = s7 * e + bfhi(cur.w);
    }
}

// ---------------------------------------------------------------------------
// Kernel C: out[i][e] = out_intra[i][e] + dfs[i] * sum_d q[i][d] * S_c[d][e].
// Swapped MFMA (A = stateT rows e, B = q rows i) -> C[e][i]; out_intra read
// as bf16 (outi) when available, else f32 RMW through out.
// ---------------------------------------------------------------------------
__global__ __launch_bounds__(256) void gdn_inter(
    const float* __restrict__ q, const unsigned short* __restrict__ state,
    const float* __restrict__ dfs_buf, const unsigned short* __restrict__ outi,
    float* __restrict__ out)
{
    const int blk = blockIdx.x, g = blk >> 6, c = blk & 63;
    const int tid = threadIdx.x, lane = tid & 63, w = tid >> 6;
    const int m16 = lane & 15, quad = lane >> 4;
    const size_t base  = ((size_t)g * Sp + (size_t)c * BTp) * Dp;
    const size_t bbase = (size_t)g * Sp + (size_t)c * BTp;
    const unsigned short* sb = state + (size_t)blk * Dp * Dp;
    const int i = 16 * w + m16;                    // this lane's output row

    const float scale = dfs_buf[bbase + i];
    bf16x8 qf[4];
    const float* qrow = q + base + (size_t)i * Dp + quad * 8;
    #pragma unroll
    for (int ks = 0; ks < 4; ++ks) {
        const float4 a = *(const float4*)(qrow + ks * 32);
        const float4 b = *(const float4*)(qrow + ks * 32 + 4);
        union { bf16x8 v; unsigned ui[4]; } t;
        t.ui[0] = pack2(a.x * scale, a.y * scale);
        t.ui[1] = pack2(a.z * scale, a.w * scale);
        t.ui[2] = pack2(b.x * scale, b.y * scale);
        t.ui[3] = pack2(b.z * scale, b.w * scale);
        qf[ks] = t.v;
    }

    // preload the += operand while MFMAs run
    float ovf[8][4];
    if (outi) {
        #pragma unroll
        for (int nt = 0; nt < 8; ++nt) {
            const uint2 pw = *(const uint2*)&outi[base + (size_t)i * Dp + 16 * nt + 4 * quad];
            ovf[nt][0] = bflo(pw.x); ovf[nt][1] = bfhi(pw.x);
            ovf[nt][2] = bflo(pw.y); ovf[nt][3] = bfhi(pw.y);
        }
    } else {
        #pragma unroll
        for (int nt = 0; nt < 8; ++nt) {
            const float4 o = *(const float4*)&out[base + (size_t)i * Dp + 16 * nt + 4 * quad];
            ovf[nt][0] = o.x; ovf[nt][1] = o.y; ovf[nt][2] = o.z; ovf[nt][3] = o.w;
        }
    }

    f32x4 acc[8] = {};
    #pragma unroll
    for (int ks = 0; ks < 4; ++ks) {
        bf16x8 afr[8];
        #pragma unroll
        for (int nt = 0; nt < 8; ++nt)
            afr[nt] = *(const bf16x8*)(sb + (16 * nt + m16) * Dp + quad * 8 + ks * 32);
        #pragma unroll
        for (int nt = 0; nt < 8; ++nt)
            acc[nt] = MFMA(afr[nt], qf[ks], acc[nt]);   // C[e][i]
    }
    #pragma unroll
    for (int nt = 0; nt < 8; ++nt) {
        float4 st;
        st.x = ovf[nt][0] + acc[nt][0]; st.y = ovf[nt][1] + acc[nt][1];
        st.z = ovf[nt][2] + acc[nt][2]; st.w = ovf[nt][3] + acc[nt][3];
        *(float4*)&out[base + (size_t)i * Dp + 16 * nt + 4 * quad] = st;
    }
}

// ---------------------------------------------------------------------------
extern "C" void kernel_launch(void* const* d_in, const int* in_sizes, int n_in,
                              void* d_out, int out_size, void* d_ws, size_t ws_size,
                              hipStream_t stream) {
    const float* q    = (const float*)d_in[0];
    const float* k    = (const float*)d_in[1];
    const float* v    = (const float*)d_in[2];
    const float* beta = (const float*)d_in[3];
    float* out = (float*)d_out;

    unsigned short* upd = (unsigned short*)d_ws;             // G*NC*D*D bf16 (updT/stateT)
    float* tot_buf = (float*)(upd + (size_t)Gp * NCp * Dp * Dp);
    float* dfs_buf = tot_buf + Gp * NCp;
    float* cum_buf = dfs_buf + (size_t)Gp * Sp;
    float* dte_buf = cum_buf + (size_t)Gp * Sp;
    unsigned short* outi = (unsigned short*)(dte_buf + (size_t)Gp * Sp);
    const size_t need = (size_t)((char*)(outi + (size_t)Gp * Sp * Dp) - (char*)d_ws);
    if (ws_size < need) outi = nullptr;    // fallback: f32 RMW through out

    gdn_beta <<<Gp * NCp / 4, 256, 0, stream>>>(beta, cum_buf, dte_buf, dfs_buf, tot_buf);
    gdn_intra<<<Gp * NCp, 256, 0, stream>>>(q, k, v, cum_buf, dte_buf, out, outi, upd);
    gdn_scan <<<Gp * 16, 128, 0, stream>>>(upd, tot_buf);
    gdn_inter<<<Gp * NCp, 256, 0, stream>>>(q, upd, dfs_buf, outi, out);
}